// Round 1
// baseline (736.632 us; speedup 1.0000x reference)
//
#include <hip/hip_runtime.h>

#define HDIM 768

typedef _Float16 f16x8 __attribute__((ext_vector_type(8)));
typedef _Float16 f16x4 __attribute__((ext_vector_type(4)));
typedef float f32x4 __attribute__((ext_vector_type(4)));

// ---- workspace layout (bytes) ----
// W16   : 768*768*2      = 1179648
// e     : 131072*4       =  524288   (unnormalized exp(score) per row)
// Z     : 4              (sum of e)
// part  : 1024*768*4     = 3145728   (per-block partial weighted sums)
#define WS_W16  0
#define WS_E    1179648
#define WS_Z    1703936
#define WS_PART 1704192
// total ~4.85 MB

__device__ __forceinline__ float tanh_fast(float z) {
    // tanh(z) = 1 - 2/(exp(2z)+1); safe at both extremes (inf -> 1, 0 -> -1)
    float e2 = __expf(2.0f * z);
    return 1.0f - 2.0f / (e2 + 1.0f);
}

// ---------------- kernel 1: convert W to fp16, zero Z ----------------
__global__ __launch_bounds__(1024) void prep_kernel(
    const float* __restrict__ W, _Float16* __restrict__ W16, float* __restrict__ Z) {
    int idx = blockIdx.x * 1024 + threadIdx.x;
    if (idx < HDIM * HDIM) W16[idx] = (_Float16)W[idx];
    if (idx == 0) *Z = 0.0f;
}

// ---------------- kernel 2: fused GEMM + tanh + v-dot + exp ----------------
// block = 1024 threads (16 waves), 64 rows of h per block.
// waves: 2 row-groups x 8 col-groups. col chunks: 2 x 384 cols, C=3 tiles/wave.
// A (h tile) staged in LDS as fp16, row pad +8 halves (stride 1552 B).
// B fragments read directly from global W16 (L2-resident), 8 contiguous k/lane.
__global__ __launch_bounds__(1024) void score_kernel(
    const float* __restrict__ h, const _Float16* __restrict__ W16,
    const float* __restrict__ bias, const float* __restrict__ vvec,
    float* __restrict__ e_out, float* __restrict__ Z) {

    extern __shared__ char lds[];
    _Float16* As = (_Float16*)lds;                      // [64][776] fp16
    float* s_red = (float*)(lds + 64 * 776 * 2);        // [8 colgroups][64 rows]

    const int tid  = threadIdx.x;
    const int row0 = blockIdx.x * 64;

    // ---- stage A: 64 x 768 fp32 -> fp16 in LDS (float4 loads) ----
    #pragma unroll
    for (int i = 0; i < 12; ++i) {
        int flat = i * 1024 + tid;            // 0..12287 (64 rows * 192 float4)
        int r  = flat / 192;
        int k4 = flat - r * 192;
        f32x4 f = *reinterpret_cast<const f32x4*>(h + (size_t)(row0 + r) * HDIM + k4 * 4);
        f16x4 hv;
        hv[0] = (_Float16)f[0]; hv[1] = (_Float16)f[1];
        hv[2] = (_Float16)f[2]; hv[3] = (_Float16)f[3];
        *reinterpret_cast<f16x4*>(As + r * 776 + k4 * 4) = hv;
    }
    __syncthreads();

    const int lane     = tid & 63;
    const int wave     = tid >> 6;      // 0..15
    const int rowgroup = wave >> 3;     // 0..1  (32 rows each)
    const int colgroup = wave & 7;      // 0..7  (48 cols each per chunk)
    const int l15      = lane & 15;
    const int lhi      = lane >> 4;     // 0..3

    float p[2][4] = {{0.f,0.f,0.f,0.f},{0.f,0.f,0.f,0.f}};

    #pragma unroll
    for (int chunk = 0; chunk < 2; ++chunk) {
        f32x4 acc[2][3];
        #pragma unroll
        for (int rt = 0; rt < 2; ++rt)
            #pragma unroll
            for (int ct = 0; ct < 3; ++ct)
                acc[rt][ct] = (f32x4){0.f, 0.f, 0.f, 0.f};

        const int colbase = chunk * 384 + colgroup * 48;

        for (int kt = 0; kt < 24; ++kt) {
            const int k0 = kt * 32 + lhi * 8;
            // A fragments: row = lane&15 (+16 for rt=1), k = k0..k0+7
            f16x8 a0 = *reinterpret_cast<const f16x8*>(As + (rowgroup * 32 + l15) * 776 + k0);
            f16x8 a1 = *reinterpret_cast<const f16x8*>(As + (rowgroup * 32 + 16 + l15) * 776 + k0);
            // B fragments: col j = lane&15 within tile, k = k0..k0+7 -> W16[j][k] contiguous
            f16x8 b0 = *reinterpret_cast<const f16x8*>(W16 + (size_t)(colbase + l15) * HDIM + k0);
            f16x8 b1 = *reinterpret_cast<const f16x8*>(W16 + (size_t)(colbase + 16 + l15) * HDIM + k0);
            f16x8 b2 = *reinterpret_cast<const f16x8*>(W16 + (size_t)(colbase + 32 + l15) * HDIM + k0);

            acc[0][0] = __builtin_amdgcn_mfma_f32_16x16x32_f16(a0, b0, acc[0][0], 0, 0, 0);
            acc[0][1] = __builtin_amdgcn_mfma_f32_16x16x32_f16(a0, b1, acc[0][1], 0, 0, 0);
            acc[0][2] = __builtin_amdgcn_mfma_f32_16x16x32_f16(a0, b2, acc[0][2], 0, 0, 0);
            acc[1][0] = __builtin_amdgcn_mfma_f32_16x16x32_f16(a1, b0, acc[1][0], 0, 0, 0);
            acc[1][1] = __builtin_amdgcn_mfma_f32_16x16x32_f16(a1, b1, acc[1][1], 0, 0, 0);
            acc[1][2] = __builtin_amdgcn_mfma_f32_16x16x32_f16(a1, b2, acc[1][2], 0, 0, 0);
        }

        // epilogue: z = acc + bias; p += v * tanh(z)
        #pragma unroll
        for (int ct = 0; ct < 3; ++ct) {
            int j = colbase + ct * 16 + l15;
            float bj = bias[j];
            float vj = vvec[j];
            #pragma unroll
            for (int rt = 0; rt < 2; ++rt)
                #pragma unroll
                for (int r = 0; r < 4; ++r) {
                    float t = tanh_fast(acc[rt][ct][r] + bj);
                    p[rt][r] = fmaf(vj, t, p[rt][r]);
                }
        }
    }

    // reduce p over the 16 lanes holding the 16 cols of each tile
    #pragma unroll
    for (int rt = 0; rt < 2; ++rt)
        #pragma unroll
        for (int r = 0; r < 4; ++r) {
            float x = p[rt][r];
            x += __shfl_xor(x, 1);
            x += __shfl_xor(x, 2);
            x += __shfl_xor(x, 4);
            x += __shfl_xor(x, 8);
            if (l15 == 0)
                s_red[colgroup * 64 + rowgroup * 32 + rt * 16 + lhi * 4 + r] = x;
        }
    __syncthreads();

    // final: sum across 8 colgroups, exp, store, block-sum -> atomicAdd(Z)
    if (tid < 64) {
        float s = 0.f;
        #pragma unroll
        for (int cg = 0; cg < 8; ++cg) s += s_red[cg * 64 + tid];
        float e = __expf(s);                 // |s| <= ||v||_1 <= ~61: no overflow
        e_out[row0 + tid] = e;
        float tot = e;
        tot += __shfl_xor(tot, 1);
        tot += __shfl_xor(tot, 2);
        tot += __shfl_xor(tot, 4);
        tot += __shfl_xor(tot, 8);
        tot += __shfl_xor(tot, 16);
        tot += __shfl_xor(tot, 32);
        if (tid == 0) atomicAdd(Z, tot);
    }
}

// ---------------- kernel 3: partial weighted sums  part[b][j] = sum e_i h_ij ----------------
__global__ __launch_bounds__(192) void wsum_kernel(
    const float* __restrict__ h, const float* __restrict__ e_s,
    float* __restrict__ part, int rows_per_block) {
    const int t = threadIdx.x;                  // 192 threads * 4 cols = 768
    const int row0 = blockIdx.x * rows_per_block;
    f32x4 acc = {0.f, 0.f, 0.f, 0.f};
    const float* hp = h + (size_t)row0 * HDIM + t * 4;
    #pragma unroll 4
    for (int r = 0; r < rows_per_block; ++r) {
        float e = e_s[row0 + r];
        f32x4 hv = *reinterpret_cast<const f32x4*>(hp + (size_t)r * HDIM);
        acc[0] = fmaf(e, hv[0], acc[0]);
        acc[1] = fmaf(e, hv[1], acc[1]);
        acc[2] = fmaf(e, hv[2], acc[2]);
        acc[3] = fmaf(e, hv[3], acc[3]);
    }
    *reinterpret_cast<f32x4*>(part + (size_t)blockIdx.x * HDIM + t * 4) = acc;
}

// ---------------- kernel 4: out[j] = sum_b part[b][j] / Z ----------------
__global__ __launch_bounds__(128) void finalize_kernel(
    const float* __restrict__ part, const float* __restrict__ Z,
    float* __restrict__ out, int nparts) {
    const int col = blockIdx.x * 128 + threadIdx.x;
    float s = 0.f;
    #pragma unroll 8
    for (int p = 0; p < nparts; ++p) s += part[(size_t)p * HDIM + col];
    out[col] = s / (*Z);
}

extern "C" void kernel_launch(void* const* d_in, const int* in_sizes, int n_in,
                              void* d_out, int out_size, void* d_ws, size_t ws_size,
                              hipStream_t stream) {
    const float* h    = (const float*)d_in[0];   // [N, 768]
    const float* W    = (const float*)d_in[1];   // [768, 768]
    const float* bias = (const float*)d_in[2];   // [768]
    const float* vv   = (const float*)d_in[3];   // [1, 768]
    float* out = (float*)d_out;                  // [1, 768] fp32

    const int n = in_sizes[0] / HDIM;            // 131072

    char* ws = (char*)d_ws;
    _Float16* W16 = (_Float16*)(ws + WS_W16);
    float* e_s    = (float*)(ws + WS_E);
    float* Z      = (float*)(ws + WS_Z);
    float* part   = (float*)(ws + WS_PART);

    // 1) W -> fp16, zero Z
    prep_kernel<<<(HDIM * HDIM + 1023) / 1024, 1024, 0, stream>>>(W, W16, Z);

    // 2) fused GEMM/tanh/v-dot/exp: 64 rows per block
    const int lds_bytes = 64 * 776 * 2 + 8 * 64 * 4;   // 101376
    score_kernel<<<n / 64, 1024, lds_bytes, stream>>>(h, W16, bias, vv, e_s, Z);

    // 3) weighted partial sums
    const int nb2 = 1024;
    wsum_kernel<<<nb2, 192, 0, stream>>>(h, e_s, part, n / nb2);

    // 4) finalize
    finalize_kernel<<<HDIM / 128, 128, 0, stream>>>(part, Z, out, nb2);
}

// Round 2
// 426.606 us; speedup vs baseline: 1.7267x; 1.7267x over previous
//
#include <hip/hip_runtime.h>

#define HDIM 768
#define BM 128              // rows per block (4 waves x 32)
#define NCT 48              // col-tiles of 16
#define BSTRIDE 1600        // bytes per col in LDS B tile (1536 data + 64 pad)
#define BTILE (16 * BSTRIDE)        // 25600 bytes per buffer
#define STAGE_INSTS (BTILE / 1024)  // 25 global_load_lds per tile

typedef _Float16 f16x8 __attribute__((ext_vector_type(8)));
typedef float f32x4 __attribute__((ext_vector_type(4)));

// ---- workspace layout (bytes) ----
#define WS_W16   0            // 768*768*2 = 1179648
#define WS_Z     1179648      // 4
#define WS_PART  1179712      // 1024*768*4 = 3145728
#define WS_PART2 4325440      // 8*768*4 = 24576  (total 4350016 < round-0's 4.85MB)

__device__ __forceinline__ float tanh_fast(float z) {
    float e2 = __expf(2.0f * z);
    return 1.0f - 2.0f / (e2 + 1.0f);
}

__device__ __forceinline__ void stage16(const void* g, void* l) {
    __builtin_amdgcn_global_load_lds(
        (const __attribute__((address_space(1))) void*)g,
        (__attribute__((address_space(3))) void*)l, 16, 0, 0);
}

// ---------------- kernel 1: convert W to fp16, zero Z ----------------
__global__ __launch_bounds__(1024) void prep_kernel(
    const float* __restrict__ W, _Float16* __restrict__ W16, float* __restrict__ Z) {
    int idx = blockIdx.x * 1024 + threadIdx.x;
    if (idx < HDIM * HDIM) W16[idx] = (_Float16)W[idx];
    if (idx == 0) *Z = 0.0f;
}

// ---------------- kernel 2: fused GEMM + tanh + v-dot + exp + weighted sum ----------------
// 256 threads (4 waves), 128 rows/block, grid 1024. A in VGPRs (fp16, 48 frags/lane),
// B double-buffered in LDS via global_load_lds, 48 col-tiles of 16.
__global__ __launch_bounds__(256, 2) void score_fused_kernel(
    const float* __restrict__ h, const _Float16* __restrict__ W16,
    const float* __restrict__ bias, const float* __restrict__ vvec,
    float* __restrict__ part, float* __restrict__ Z) {

    extern __shared__ char smem[];
    float* bias_s = (float*)(smem + 2 * BTILE);          // 51200: 768 f32
    float* v_s    = (float*)(smem + 2 * BTILE + 3072);   // 54272: 768 f32
    float* e_lds  = (float*)(smem + 2 * BTILE + 6144);   // 57344: 4*32 f32
    float* zred   = (float*)(smem + 2 * BTILE + 6656);   // 57856: 4 f32
    float* wstage = (float*)smem;                        // reuse buf area: 4*768 f32

    const int tid  = threadIdx.x;
    const int wave = tid >> 6;
    const int lane = tid & 63;
    const int l15  = lane & 15;
    const int lhi  = lane >> 4;
    const int row0 = blockIdx.x * BM + wave * 32;

    // stage bias / v into LDS
    for (int j = tid; j < HDIM; j += 256) { bias_s[j] = bias[j]; v_s[j] = vvec[j]; }

    // per-lane staging source offsets: LDS-linear o -> (col c, byte b) -> W16 offset
    int soff[7];
    #pragma unroll
    for (int s = 0; s < 7; ++s) {
        int i = wave + 4 * s;
        int o = i * 1024 + lane * 16;
        int c = o / BSTRIDE;
        int b = o - c * BSTRIDE;
        if (b > 1520) b = 1520;          // pad region (never read): clamp in-bounds
        soff[s] = c * 1536 + b;
    }

    // stage col-tile 0 into buf0
    {
        const char* g = (const char*)W16;
        #pragma unroll
        for (int s = 0; s < 7; ++s)
            if (wave + 4 * s < STAGE_INSTS)
                stage16(g + soff[s], smem + (wave + 4 * s) * 1024);
    }

    // ---- load A: 32 rows x 768 K as fp16 fragments in VGPRs ----
    f16x8 a[2][24];
    const float* hbase = h + (size_t)row0 * HDIM;
    #pragma unroll
    for (int rt = 0; rt < 2; ++rt) {
        const float* hr = hbase + (size_t)(rt * 16 + l15) * HDIM + lhi * 8;
        #pragma unroll
        for (int kt = 0; kt < 24; ++kt) {
            f32x4 x0 = *(const f32x4*)(hr + kt * 32);
            f32x4 x1 = *(const f32x4*)(hr + kt * 32 + 4);
            f16x8 f;
            f[0] = (_Float16)x0[0]; f[1] = (_Float16)x0[1];
            f[2] = (_Float16)x0[2]; f[3] = (_Float16)x0[3];
            f[4] = (_Float16)x1[0]; f[5] = (_Float16)x1[1];
            f[6] = (_Float16)x1[2]; f[7] = (_Float16)x1[3];
            a[rt][kt] = f;
        }
    }

    __syncthreads();   // drains vmcnt: stage(0) + A-loads complete

    float p0[4] = {0.f, 0.f, 0.f, 0.f};
    float p1[4] = {0.f, 0.f, 0.f, 0.f};

    for (int ct = 0; ct < NCT; ++ct) {
        const int buf = ct & 1;
        // issue stage of next tile into the other buffer
        if (ct + 1 < NCT) {
            const char* g = (const char*)W16 + (ct + 1) * 24576;
            char* ldsb = smem + (buf ^ 1) * BTILE;
            #pragma unroll
            for (int s = 0; s < 7; ++s)
                if (wave + 4 * s < STAGE_INSTS)
                    stage16(g + soff[s], ldsb + (wave + 4 * s) * 1024);
        }
        // compute current tile: 24 k-steps, B-frag shared across 2 row-tiles
        const char* bfrag_base = smem + buf * BTILE + l15 * BSTRIDE + lhi * 16;
        f32x4 acc0 = {0.f, 0.f, 0.f, 0.f};
        f32x4 acc1 = {0.f, 0.f, 0.f, 0.f};
        #pragma unroll
        for (int kt = 0; kt < 24; ++kt) {
            f16x8 bfr = *(const f16x8*)(bfrag_base + kt * 64);
            acc0 = __builtin_amdgcn_mfma_f32_16x16x32_f16(a[0][kt], bfr, acc0, 0, 0, 0);
            acc1 = __builtin_amdgcn_mfma_f32_16x16x32_f16(a[1][kt], bfr, acc1, 0, 0, 0);
        }
        // epilogue: p += v_j * tanh(z + b_j) for this tile's 16 cols (col = ct*16 + l15)
        float bj = bias_s[ct * 16 + l15];
        float vj = v_s[ct * 16 + l15];
        #pragma unroll
        for (int r = 0; r < 4; ++r) {
            p0[r] = fmaf(vj, tanh_fast(acc0[r] + bj), p0[r]);
            p1[r] = fmaf(vj, tanh_fast(acc1[r] + bj), p1[r]);
        }
        __syncthreads();   // next buffer fully staged (vmcnt drained), all waves done reading
    }

    // ---- scores: reduce p over the 16 l15 lanes (cols) ----
    #pragma unroll
    for (int r = 0; r < 4; ++r) {
        #pragma unroll
        for (int m = 1; m <= 8; m <<= 1) {
            p0[r] += __shfl_xor(p0[r], m);
            p1[r] += __shfl_xor(p1[r], m);
        }
    }
    // e = exp(s); rows held: rt*16 + lhi*4 + r  (duplicated across 16 l15 lanes)
    float e0[4], e1[4];
    float zsum = 0.f;
    #pragma unroll
    for (int r = 0; r < 4; ++r) {
        e0[r] = __expf(p0[r]);
        e1[r] = __expf(p1[r]);
        zsum += e0[r] + e1[r];
    }
    // wave Z: sum across the 4 lhi groups (duplicates within group collapse via xor-16/32)
    zsum += __shfl_xor(zsum, 16);
    zsum += __shfl_xor(zsum, 32);
    if (lane == 0) zred[wave] = zsum;
    if (l15 == 0) {
        #pragma unroll
        for (int r = 0; r < 4; ++r) {
            e_lds[wave * 32 + lhi * 4 + r]      = e0[r];
            e_lds[wave * 32 + 16 + lhi * 4 + r] = e1[r];
        }
    }
    __syncthreads();

    // ---- fused weighted sum: wstage[wave][j] = sum over wave's 32 rows of e_i * h_ij ----
    float er0 = e_lds[wave * 32 + l15];
    float er1 = e_lds[wave * 32 + 16 + l15];
    #pragma unroll
    for (int kt = 0; kt < 24; ++kt) {
        float w[8];
        #pragma unroll
        for (int e = 0; e < 8; ++e)
            w[e] = er0 * (float)a[0][kt][e] + er1 * (float)a[1][kt][e];
        #pragma unroll
        for (int e = 0; e < 8; ++e) {
            #pragma unroll
            for (int m = 1; m <= 8; m <<= 1) w[e] += __shfl_xor(w[e], m);
        }
        if (l15 == 0) {   // j = kt*32 + lhi*8 + e
            f32x4 w0 = {w[0], w[1], w[2], w[3]};
            f32x4 w1 = {w[4], w[5], w[6], w[7]};
            *(f32x4*)(wstage + wave * HDIM + kt * 32 + lhi * 8)     = w0;
            *(f32x4*)(wstage + wave * HDIM + kt * 32 + lhi * 8 + 4) = w1;
        }
    }
    __syncthreads();

    // cross-wave partial + block Z
    for (int j = tid; j < HDIM; j += 256) {
        float s = wstage[j] + wstage[HDIM + j] + wstage[2 * HDIM + j] + wstage[3 * HDIM + j];
        part[(size_t)blockIdx.x * HDIM + j] = s;
    }
    if (tid == 0) atomicAdd(Z, zred[0] + zred[1] + zred[2] + zred[3]);
}

// ---------------- finalize stage 1: sum 1024 parts in groups of 128 ----------------
__global__ __launch_bounds__(128) void fin1_kernel(
    const float* __restrict__ part, float* __restrict__ part2) {
    const int g  = blockIdx.x / 6;           // part-group 0..7
    const int cb = blockIdx.x % 6;
    const int col = cb * 128 + threadIdx.x;
    float s = 0.f;
    #pragma unroll 8
    for (int p = g * 128; p < (g + 1) * 128; ++p) s += part[(size_t)p * HDIM + col];
    part2[g * HDIM + col] = s;
}

// ---------------- finalize stage 2: out[j] = sum_g part2[g][j] / Z ----------------
__global__ __launch_bounds__(128) void fin2_kernel(
    const float* __restrict__ part2, const float* __restrict__ Z,
    float* __restrict__ out) {
    const int col = blockIdx.x * 128 + threadIdx.x;
    float s = 0.f;
    #pragma unroll
    for (int g = 0; g < 8; ++g) s += part2[g * HDIM + col];
    out[col] = s / (*Z);
}

extern "C" void kernel_launch(void* const* d_in, const int* in_sizes, int n_in,
                              void* d_out, int out_size, void* d_ws, size_t ws_size,
                              hipStream_t stream) {
    const float* h    = (const float*)d_in[0];   // [N, 768]
    const float* W    = (const float*)d_in[1];   // [768, 768]
    const float* bias = (const float*)d_in[2];   // [768]
    const float* vv   = (const float*)d_in[3];   // [1, 768]
    float* out = (float*)d_out;                  // [1, 768] fp32

    const int n = in_sizes[0] / HDIM;            // 131072

    char* ws = (char*)d_ws;
    _Float16* W16 = (_Float16*)(ws + WS_W16);
    float* Z      = (float*)(ws + WS_Z);
    float* part   = (float*)(ws + WS_PART);
    float* part2  = (float*)(ws + WS_PART2);

    // 1) W -> fp16, zero Z
    prep_kernel<<<(HDIM * HDIM + 1023) / 1024, 1024, 0, stream>>>(W, W16, Z);

    // 2) fused score + exp + weighted-sum partials
    const int lds_bytes = 2 * BTILE + 6144 + 512 + 64;   // 57920
    score_fused_kernel<<<n / BM, 256, lds_bytes, stream>>>(h, W16, bias, vv, part, Z);

    // 3) reduce partials
    fin1_kernel<<<48, 128, 0, stream>>>(part, part2);
    fin2_kernel<<<HDIM / 128, 128, 0, stream>>>(part2, Z, out);
}